// Round 3
// baseline (230.371 us; speedup 1.0000x reference)
//
#include <hip/hip_runtime.h>
#include <cstdint>
#include <cstddef>

// ---------------------------------------------------------------------------
// Hgru2 (GLA-style gated linear attention), B=4, N=2048, d=1024, h=8, hd=128
//   cast_all: x,W -> bf16 (Wo gets norm_w folded); zeroes Ssum
//   gemm_qkv: Q=silu(xWq^T), K=1-sigmoid(xWk^T) (bf16), V (bf16)
//   hgru_scan (C=32): recompute U_{c-1} from chunk c-1 (1-term state, decay
//       <= e^-10); O = tril(Qh Kt^T) V + Qh U; fused sumsq via atomicAdd.
//   gemm_out: out[m][n] = rsqrt(Ssum[m]/1024+eps) * (O @ (Wo . w)^T)[m][n]
// R14: qkv 8-phase with DEEP staging (2 tiles ahead). Per tile kt (buf c):
//   P0: read A-lo(8)+B-lo(4) | bar | M00 | bar
//   P1: read B-hi(4)         | bar | M01 | bar      (B halves dead after P1)
//   P2: read A-hi(8); stage B(kt+2)->buf c | bar | M10 | bar  (A dead after P2)
//   P3: stage A(kt+2)->buf c; M11; vmcnt(8); bar    (tile boundary)
//   Issue-to-use >= 5 phases (~1500 cyc) for every gload; one vmcnt/tile
//   (oldest 8 of 16 outstanding = tile kt+1's loads stay in flight).
//   Write-after-read safety: each stage slot's last reader drained lgkmcnt
//   before the barrier preceding the stage. Accum order bit-identical.
// ---------------------------------------------------------------------------

typedef unsigned short u16;
using f32x4  = __attribute__((ext_vector_type(4))) float;
using bf16x8 = __attribute__((ext_vector_type(8))) short;

__device__ __forceinline__ float bf2f(u16 u) {
  union { unsigned int i; float f; } v; v.i = ((unsigned int)u) << 16; return v.f;
}
__device__ __forceinline__ u16 f2bf(float f) {
  union { float f; unsigned int i; } v; v.f = f;
  unsigned int r = v.i + 0x7fffu + ((v.i >> 16) & 1u);
  return (u16)(r >> 16);
}
__device__ __forceinline__ void async_load16(const void* g, void* l) {
  __builtin_amdgcn_global_load_lds(
      (const __attribute__((address_space(1))) unsigned int*)(uintptr_t)g,
      (__attribute__((address_space(3))) unsigned int*)(uintptr_t)l, 16, 0, 0);
}
// logsigmoid(f) for f in (0,1): softplus series, |err| <= 2.5e-5
__device__ __forceinline__ float logsig01(float f) {
  float u = f * f;
  return -0.69314718f + 0.5f * f + u * (-0.125f + u * (0.0052083335f - u * 3.472222e-4f));
}

// ---------------------------------------------------------------------------
// 128x128-tile bf16 GEMM core (R7): BK=32, double-buffered in 32KB,
// 1 barrier/kt, loads age a full compute phase before the drain.
// (still used by hgru_gemm_out)
// ---------------------------------------------------------------------------
__device__ __forceinline__ void gemm128_core(const u16* __restrict__ Ag, const u16* __restrict__ Bg,
                                             u16* smem, f32x4 (&acc)[4][4]) {
  const int tid = threadIdx.x;
  const int lane = tid & 63, wave = tid >> 6;
  const int wm = (wave & 1) * 64, wn = (wave >> 1) * 64;
  const int r = lane & 15, quad = lane >> 4;
  const int xk = r & 3;
  const u16* baseA = smem + (wm + r) * 32 + ((quad ^ xk) & 3) * 8;
  const u16* baseB = smem + 4096 + (wn + r) * 32 + ((quad ^ xk) & 3) * 8;
  const int soff = (tid >> 2) * 1024 + (((tid & 3) ^ ((tid >> 2) & 3)) * 8);
  u16* dA = smem + wave * 512;           // + it*2048 + buf*8192
  u16* dB = smem + 4096 + wave * 512;
#pragma unroll
  for (int it = 0; it < 2; ++it) {
    async_load16(Ag + it * 65536 + soff, dA + it * 2048);
    async_load16(Bg + it * 65536 + soff, dB + it * 2048);
  }
#pragma unroll 2
  for (int kt = 0; kt < 32; ++kt) {
    const int cb = (kt & 1) * 8192;
    __syncthreads();
    if (kt < 31) {
      const int nb = ((kt + 1) & 1) * 8192;
      const u16* As = Ag + (kt + 1) * 32 + soff;
      const u16* Bs = Bg + (kt + 1) * 32 + soff;
#pragma unroll
      for (int it = 0; it < 2; ++it) {
        async_load16(As + it * 65536, dA + nb + it * 2048);
        async_load16(Bs + it * 65536, dB + nb + it * 2048);
      }
    }
    bf16x8 af[4], bv[4];
#pragma unroll
    for (int i = 0; i < 4; ++i) af[i] = *(const bf16x8*)(baseA + cb + i * 512);
#pragma unroll
    for (int j = 0; j < 4; ++j) bv[j] = *(const bf16x8*)(baseB + cb + j * 512);
#pragma unroll
    for (int i = 0; i < 4; ++i)
#pragma unroll
      for (int j = 0; j < 4; ++j)
        acc[i][j] = __builtin_amdgcn_mfma_f32_16x16x32_bf16(af[i], bv[j], acc[i][j], 0, 0, 0);
  }
}

// ---------------------------------------------------------------------------
// merged casts + Ssum zero: blocks 0-8191 -> x; 8192-12287 -> weights
// (Wo folds norm_w); 12288-12319 -> zero Ssum (8192 f32).
__global__ __launch_bounds__(256) void cast_all(
    const float* __restrict__ x, const float* __restrict__ w0, const float* __restrict__ w1,
    const float* __restrict__ w2, const float* __restrict__ w3, const float* __restrict__ nw,
    u16* __restrict__ xd, u16* __restrict__ d0, u16* __restrict__ d1,
    u16* __restrict__ d2, u16* __restrict__ d3, float* __restrict__ Sv) {
  const int blk = blockIdx.x;
  if (blk >= 12288) {
    Sv[(blk - 12288) * 256 + threadIdx.x] = 0.f;
    return;
  }
  const float* src;
  u16* dst;
  int i;
  bool fold = false;
  if (blk < 8192) {
    src = x; dst = xd; i = blk * 256 + threadIdx.x;
  } else {
    int wb = blk - 8192, which = wb >> 10;
    i = (wb & 1023) * 256 + threadIdx.x;
    src = which == 0 ? w0 : (which == 1 ? w1 : (which == 2 ? w2 : w3));
    dst = which == 0 ? d0 : (which == 1 ? d1 : (which == 2 ? d2 : d3));
    fold = (which == 3);
  }
  float4 v = ((const float4*)src)[i];
  if (fold) {
    float4 wv = ((const float4*)nw)[i & 255];
    v.x *= wv.x; v.y *= wv.y; v.z *= wv.z; v.w *= wv.w;
  }
  unsigned int lo = (unsigned)f2bf(v.x) | ((unsigned)f2bf(v.y) << 16);
  unsigned int hi = (unsigned)f2bf(v.z) | ((unsigned)f2bf(v.w) << 16);
  ((uint2*)dst)[i] = make_uint2(lo, hi);
}

// ---------------------------------------------------------------------------
// QKV GEMM, 256x256 tile, deep-staged 8-phase K-loop. Grid: 384 x 512 thr.
// wg (XCD-swizzled) -> bm = wg/12, bn = wg%12; bn>>2 selects Q/K/V weight.
// LDS (128KB, u16 idx): A buf c at c*16384, B at 32768 + c*16384.
// Swizzle: LDS[row][chunk] = global[row][chunk ^ (row&7)]; read chunk
// (ks*4+quad)^(r&7) -> conflict-free b128 (verified: 0 conflicts in R12/13).
// ---------------------------------------------------------------------------
__global__ __launch_bounds__(512, 2) void hgru_gemm_qkv8(
    const u16* __restrict__ Xb, const u16* __restrict__ Wqb, const u16* __restrict__ Wkb,
    const u16* __restrict__ Wvb, u16* __restrict__ Qb, u16* __restrict__ Kb,
    u16* __restrict__ Vb) {
  __shared__ alignas(16) u16 smem[65536];  // 128 KB
  const int tid = threadIdx.x;
  const int bid = blockIdx.x;
  const int wg = (bid & 7) * 48 + (bid >> 3);          // bijective: 384 % 8 == 0
  const int bm = wg / 12, bn = wg % 12;
  const int which = bn >> 2;                            // 0=Q,1=K,2=V (block-uniform)
  const u16* __restrict__ Ag = Xb + (size_t)bm * 256 * 1024;
  const u16* __restrict__ Wm = which == 0 ? Wqb : (which == 1 ? Wkb : Wvb);
  const u16* __restrict__ Bg = Wm + (size_t)(bn & 3) * 256 * 1024;

  const int lane = tid & 63, wave = tid >> 6;
  const int wr = wave >> 2, wc = wave & 3;              // 2M x 4N waves
  const int r = lane & 15, quad = lane >> 4;

  // ---- staging maps (pre-swizzled global source, linear LDS dest) ----
  const int srow = tid >> 3;                            // 0..63
  const int scol = ((tid & 7) ^ (srow & 7)) * 8;        // inverse-swizzled col
  const u16* aS_g = Ag + (size_t)srow * 1024 + scol;
  const u16* bS_g = Bg + (size_t)srow * 1024 + scol;
  u16* aD = smem + wave * 512;                          // + c*16384 + h*8192 (+4096)
  u16* bD = smem + 32768 + wave * 512;

  auto stageA = [&](int c, int kt, int h) {
    async_load16(aS_g + (h * 128) * 1024 + kt * 64,      aD + c * 16384 + h * 8192);
    async_load16(aS_g + (h * 128 + 64) * 1024 + kt * 64, aD + c * 16384 + h * 8192 + 4096);
  };
  auto stageB = [&](int c, int kt, int h) {
    async_load16(bS_g + (h * 128) * 1024 + kt * 64,      bD + c * 16384 + h * 8192);
    async_load16(bS_g + (h * 128 + 64) * 1024 + kt * 64, bD + c * 16384 + h * 8192 + 4096);
  };

  // ---- fragment read bases (swizzled) ----
  const int ch0 = (quad ^ (r & 7)) * 8;                 // ks=0 chunk
  const int ch1 = ((4 | quad) ^ (r & 7)) * 8;           // ks=1 chunk
  const u16* aR = smem + (wr * 128 + r) * 64;
  const u16* bR = smem + 32768 + (wc * 64 + r) * 64;

  f32x4 acc[8][4] = {};
  bf16x8 aS[4][2];        // A-lo then A-hi (reuses regs after M01)
  bf16x8 b01[2][2], b23[2][2];

  // ---- prologue: fully stage tiles 0 (buf0) and 1 (buf1): 16 loads ----
  stageB(0, 0, 0); stageB(0, 0, 1);
  stageA(0, 0, 0); stageA(0, 0, 1);
  stageB(1, 1, 0); stageB(1, 1, 1);
  stageA(1, 1, 0); stageA(1, 1, 1);

#pragma unroll 2
  for (int kt = 0; kt < 16; ++kt) {
    const int c = kt & 1, co = c * 16384;

    // ---- tile boundary: drain tile kt's 8 loads (keep tile kt+1's 8) ----
    if (kt < 15) asm volatile("s_waitcnt vmcnt(8)" ::: "memory");
    else         asm volatile("s_waitcnt vmcnt(0)" ::: "memory");
    __builtin_amdgcn_s_barrier();

    // ---- P0: read A-lo(8) + B-lo(4) | bar | M00 | bar ----
#pragma unroll
    for (int mi = 0; mi < 4; ++mi) {
      aS[mi][0] = *(const bf16x8*)(aR + co + mi * 1024 + ch0);
      aS[mi][1] = *(const bf16x8*)(aR + co + mi * 1024 + ch1);
    }
#pragma unroll
    for (int nj = 0; nj < 2; ++nj) {
      b01[nj][0] = *(const bf16x8*)(bR + co + nj * 1024 + ch0);
      b01[nj][1] = *(const bf16x8*)(bR + co + nj * 1024 + ch1);
    }
    __builtin_amdgcn_s_barrier();
    __builtin_amdgcn_s_setprio(1);
#pragma unroll
    for (int mi = 0; mi < 4; ++mi)
#pragma unroll
      for (int nj = 0; nj < 2; ++nj) {
        acc[mi][nj] = __builtin_amdgcn_mfma_f32_16x16x32_bf16(aS[mi][0], b01[nj][0], acc[mi][nj], 0, 0, 0);
        acc[mi][nj] = __builtin_amdgcn_mfma_f32_16x16x32_bf16(aS[mi][1], b01[nj][1], acc[mi][nj], 0, 0, 0);
      }
    __builtin_amdgcn_s_setprio(0);
    __builtin_amdgcn_s_barrier();

    // ---- P1: read B-hi(4) | bar | M01 | bar  (B halves dead after this) ----
#pragma unroll
    for (int nj = 0; nj < 2; ++nj) {
      b23[nj][0] = *(const bf16x8*)(bR + co + (nj + 2) * 1024 + ch0);
      b23[nj][1] = *(const bf16x8*)(bR + co + (nj + 2) * 1024 + ch1);
    }
    __builtin_amdgcn_s_barrier();
    __builtin_amdgcn_s_setprio(1);
#pragma unroll
    for (int mi = 0; mi < 4; ++mi)
#pragma unroll
      for (int nj = 0; nj < 2; ++nj) {
        acc[mi][nj + 2] = __builtin_amdgcn_mfma_f32_16x16x32_bf16(aS[mi][0], b23[nj][0], acc[mi][nj + 2], 0, 0, 0);
        acc[mi][nj + 2] = __builtin_amdgcn_mfma_f32_16x16x32_bf16(aS[mi][1], b23[nj][1], acc[mi][nj + 2], 0, 0, 0);
      }
    __builtin_amdgcn_s_setprio(0);
    __builtin_amdgcn_s_barrier();

    // ---- P2: read A-hi(8); stage B(kt+2) -> buf c | bar | M10 | bar ----
#pragma unroll
    for (int mi = 0; mi < 4; ++mi) {
      aS[mi][0] = *(const bf16x8*)(aR + co + (mi + 4) * 1024 + ch0);
      aS[mi][1] = *(const bf16x8*)(aR + co + (mi + 4) * 1024 + ch1);
    }
    if (kt < 14) { stageB(c, kt + 2, 0); stageB(c, kt + 2, 1); }
    __builtin_amdgcn_s_barrier();
    __builtin_amdgcn_s_setprio(1);
#pragma unroll
    for (int mi = 0; mi < 4; ++mi)
#pragma unroll
      for (int nj = 0; nj < 2; ++nj) {
        acc[mi + 4][nj] = __builtin_amdgcn_mfma_f32_16x16x32_bf16(aS[mi][0], b01[nj][0], acc[mi + 4][nj], 0, 0, 0);
        acc[mi + 4][nj] = __builtin_amdgcn_mfma_f32_16x16x32_bf16(aS[mi][1], b01[nj][1], acc[mi + 4][nj], 0, 0, 0);
      }
    __builtin_amdgcn_s_setprio(0);
    __builtin_amdgcn_s_barrier();

    // ---- P3: stage A(kt+2) -> buf c; M11; (vmcnt+bar at next loop top) ----
    if (kt < 14) { stageA(c, kt + 2, 0); stageA(c, kt + 2, 1); }
    __builtin_amdgcn_s_setprio(1);
#pragma unroll
    for (int mi = 0; mi < 4; ++mi)
#pragma unroll
      for (int nj = 0; nj < 2; ++nj) {
        acc[mi + 4][nj + 2] = __builtin_amdgcn_mfma_f32_16x16x32_bf16(aS[mi][0], b23[nj][0], acc[mi + 4][nj + 2], 0, 0, 0);
        acc[mi + 4][nj + 2] = __builtin_amdgcn_mfma_f32_16x16x32_bf16(aS[mi][1], b23[nj][1], acc[mi + 4][nj + 2], 0, 0, 0);
      }
    __builtin_amdgcn_s_setprio(0);
  }

  // ---- epilogue: activation + store (which is block-uniform) ----
  u16* __restrict__ dst = which == 0 ? Qb : (which == 1 ? Kb : Vb);
  const int nbase = (bn & 3) * 256 + wc * 64;
  const int mbase = bm * 256 + wr * 128 + quad * 4;
#pragma unroll
  for (int mi = 0; mi < 8; ++mi)
#pragma unroll
    for (int nj = 0; nj < 4; ++nj)
#pragma unroll
      for (int reg = 0; reg < 4; ++reg) {
        int m = mbase + mi * 16 + reg;
        int n = nbase + nj * 16 + r;
        float z = acc[mi][nj][reg];
        float v;
        if (which == 0)      v = z / (1.f + __expf(-z));           // silu
        else if (which == 1) { float ek = __expf(-z); v = ek / (1.f + ek); }  // 1-sigmoid
        else                 v = z;
        dst[(size_t)m * 1024 + n] = f2bf(v);
      }
}

// ---------------------------------------------------------------------------
// Fused scan, 4-barrier structure, LDS 40448 B -> 4 blocks/CU.
// grid 4096: vh = blk&1, c = (blk>>1)&63 (C=32), bh = blk>>7.
// P0: column-owner cumsum+transforms (the ONLY global-latency phase)
//     half 0 (tid<128, col i): chunk c-1, 2-pass -> sKt[i][s] = k*exp(bC-b_s)
//     half 1 (col j): chunk c, 1-pass -> sQ[t][j]=q*exp(b), sK[t][j]=k*exp(-b)
//     all: V^T scatters from uint4-prefetched regs.
// P1: U-GEMM (regs) + GEMM1 -> sAm.   P2: spill U -> sU (overlays dead sKt).
// P3: GEMM2 + ssq atomics + stage O tile in sO.   P4: coalesced uint4 O-store.
// ---------------------------------------------------------------------------
__global__ __launch_bounds__(256, 4) void hgru_scan(
    const u16* __restrict__ Qg, const u16* __restrict__ Kg, const u16* __restrict__ Vg,
    u16* __restrict__ O, float* __restrict__ Ssum) {
  __shared__ alignas(16) char smem[40448];
  u16* sKt  = (u16*)(smem);                // [128][40] khat^T   [0,10240)
  u16* sVt1 = (u16*)(smem + 10240);        // [64][40]  V^T c-1  [10240,15360)
  u16* sK   = (u16*)(smem + 15360);        // [32][136] Kt       [15360,24064)
  u16* sQ   = (u16*)(smem + 24064);        // [32][136] Qh       [24064,32768)
  u16* sVt2 = (u16*)(smem + 32768);        // [64][40]  V^T c    [32768,37888)
  u16* sAm  = (u16*)(smem + 37888);        // [32][40]  masked A [37888,40448)
  u16* sU   = (u16*)(smem);                // [64][136] U^T      (after B1, over dead sKt+sVt1)
  u16* sO   = (u16*)(smem + 17408);        // [32][72]  O tile   (after B1, in dead sK head)

  const int tid = threadIdx.x, blk = blockIdx.x;
  const int vh = blk & 1, c = (blk >> 1) & 63, bh = blk >> 7, h = bh & 7, bb_ = bh >> 3;
  const size_t rb = (size_t)(bb_ * 2048 + c * 32) * 1024 + h * 128;
  const bool haveP = (c > 0);
  const size_t rb1 = haveP ? rb - 32 * 1024 : rb;

  const int lane = tid & 63, wave = tid >> 6;
  const int r = lane & 15, quad = lane >> 4;
  const int ts = tid & 31, g8 = tid >> 5;

  // V prefetch (uint4) + V^T scatters
  uint4 V2 = *(const uint4*)(Vg + rb  + (size_t)ts * 1024 + vh * 64 + g8 * 8);
  uint4 V1 = *(const uint4*)(Vg + rb1 + (size_t)ts * 1024 + vh * 64 + g8 * 8);
  { const u16* vp = (const u16*)&V2;
#pragma unroll
    for (int e = 0; e < 8; ++e) sVt2[(g8 * 8 + e) * 40 + ts] = vp[e]; }
  if (haveP) {
    const u16* vp = (const u16*)&V1;
#pragma unroll
    for (int e = 0; e < 8; ++e) sVt1[(g8 * 8 + e) * 40 + ts] = vp[e];
  }

  // P0: column cumsum + transforms
  const int col = tid & 127;
  if (tid < 128) {
    if (haveP) {
      const u16* kc = Kg + rb1 + col;
      unsigned int kraw[16];
      float bC = 0.f;
#pragma unroll
      for (int t = 0; t < 16; ++t) {
        unsigned int a = kc[(size_t)(2 * t) * 1024];
        unsigned int b = kc[(size_t)(2 * t + 1) * 1024];
        kraw[t] = a | (b << 16);
        bC += logsig01(1.f - bf2f((u16)a)) + logsig01(1.f - bf2f((u16)b));
      }
      float run = 0.f;
#pragma unroll
      for (int t = 0; t < 16; ++t) {
        float ka = bf2f((u16)(kraw[t] & 0xffff));
        float kb = bf2f((u16)(kraw[t] >> 16));
        run += logsig01(1.f - ka);
        sKt[col * 40 + 2 * t]     = f2bf(ka * __expf(bC - run));
        run += logsig01(1.f - kb);
        sKt[col * 40 + 2 * t + 1] = f2bf(kb * __expf(bC - run));
      }
    }
  } else {
    const u16* kc = Kg + rb + col;
    const u16* qc = Qg + rb + col;
    float run = 0.f;
#pragma unroll
    for (int t = 0; t < 32; ++t) {
      u16 ku = kc[(size_t)t * 1024];
      u16 qu = qc[(size_t)t * 1024];
      float kv = bf2f(ku);
      run += logsig01(1.f - kv);
      sQ[t * 136 + col] = f2bf(bf2f(qu) * __expf(run));
      sK[t * 136 + col] = f2bf(kv * __expf(-run));
    }
  }
  __syncthreads();  // B0

  // P1: U-GEMM (into regs) + GEMM1 -> sAm
  f32x4 accU[2][4] = {};
  const int vm = (wave & 1) * 32, in = (wave >> 1) * 64;
  if (haveP) {
#pragma unroll
    for (int mi = 0; mi < 2; ++mi) {
      bf16x8 af = *(const bf16x8*)(sVt1 + (vm + mi * 16 + r) * 40 + quad * 8);
#pragma unroll
      for (int nj = 0; nj < 4; ++nj) {
        bf16x8 bv = *(const bf16x8*)(sKt + (in + nj * 16 + r) * 40 + quad * 8);
        accU[mi][nj] = __builtin_amdgcn_mfma_f32_16x16x32_bf16(af, bv, accU[mi][nj], 0, 0, 0);
      }
    }
  }
  { const int mi = wave & 1, nj = wave >> 1;
    f32x4 a1 = {0.f, 0.f, 0.f, 0.f};
#pragma unroll
    for (int ks = 0; ks < 4; ++ks) {
      bf16x8 af = *(const bf16x8*)(sQ + (mi * 16 + r) * 136 + ks * 32 + quad * 8);
      bf16x8 bk = *(const bf16x8*)(sK + (nj * 16 + r) * 136 + ks * 32 + quad * 8);
      a1 = __builtin_amdgcn_mfma_f32_16x16x32_bf16(af, bk, a1, 0, 0, 0);
    }
#pragma unroll
    for (int reg = 0; reg < 4; ++reg) {
      int t = mi * 16 + quad * 4 + reg, s = nj * 16 + r;
      sAm[t * 40 + s] = (s <= t) ? f2bf(a1[reg]) : (u16)0;
    } }
  __syncthreads();  // B1

  // P2: spill U accumulator -> sU (overlays dead sKt/sVt1)
  if (haveP) {
#pragma unroll
    for (int mi = 0; mi < 2; ++mi)
#pragma unroll
      for (int nj = 0; nj < 4; ++nj)
#pragma unroll
        for (int reg = 0; reg < 4; ++reg) {
          int vl = vm + mi * 16 + quad * 4 + reg;
          int i  = in + nj * 16 + r;
          sU[vl * 136 + i] = f2bf(accU[mi][nj][reg]);
        }
  }
  __syncthreads();  // B2

  // P3: GEMM2 + fused sumsq + stage O tile
  { const int mi = wave & 1, no = (wave >> 1) * 32;
    bf16x8 af0 = *(const bf16x8*)(sAm + (mi * 16 + r) * 40 + quad * 8);
    bf16x8 afq[4];
    if (haveP) {
#pragma unroll
      for (int ks = 0; ks < 4; ++ks)
        afq[ks] = *(const bf16x8*)(sQ + (mi * 16 + r) * 136 + ks * 32 + quad * 8);
    }
    f32x4 ssq = {0.f, 0.f, 0.f, 0.f};
#pragma unroll
    for (int j = 0; j < 2; ++j) {
      f32x4 acc2 = {0.f, 0.f, 0.f, 0.f};
      bf16x8 bv0 = *(const bf16x8*)(sVt2 + (no + j * 16 + r) * 40 + quad * 8);
      acc2 = __builtin_amdgcn_mfma_f32_16x16x32_bf16(af0, bv0, acc2, 0, 0, 0);
      if (haveP) {
#pragma unroll
        for (int ks = 0; ks < 4; ++ks) {
          bf16x8 bs = *(const bf16x8*)(sU + (no + j * 16 + r) * 136 + ks * 32 + quad * 8);
          acc2 = __builtin_amdgcn_mfma_f32_16x16x32_bf16(afq[ks], bs, acc2, 0, 0, 0);
        }
      }
      ssq += acc2 * acc2;
#pragma unroll
      for (int reg = 0; reg < 4; ++reg) {
        int t = mi * 16 + quad * 4 + reg;
        sO[t * 72 + no + j * 16 + r] = f2bf(acc2[reg]);
      }
    }
    const int rowg = bb_ * 2048 + c * 32 + mi * 16 + quad * 4;
#pragma unroll
    for (int reg = 0; reg < 4; ++reg) {
      float v = ssq[reg];
      v += __shfl_xor(v, 1); v += __shfl_xor(v, 2);
      v += __shfl_xor(v, 4); v += __shfl_xor(v, 8);
      if (r == 0) atomicAdd(&Ssum[rowg + reg], v);
    } }
  __syncthreads();  // B3

  // P4: coalesced O store (uint4: 128B per 8 threads)
  { const int row = tid >> 3, seg = tid & 7;
    *(uint4*)(O + rb + (size_t)row * 1024 + vh * 64 + seg * 8) =
        *(const uint4*)(sO + row * 72 + seg * 8); }
}

// out[m][n] = rsqrt(Ssum[m]/1024+eps) * (O @ Wo'^T)[m][n]; grid (64,8)
__global__ __launch_bounds__(256) void hgru_gemm_out(const u16* __restrict__ Ab,
                                                     const u16* __restrict__ Wob,
                                                     const float* __restrict__ Ssum,
                                                     float* __restrict__ out) {
  __shared__ alignas(16) u16 smem[16384];
  const u16* Ag = Ab + (size_t)blockIdx.x * 128 * 1024;
  const u16* Bg = Wob + (size_t)blockIdx.y * 128 * 1024;
  f32x4 acc[4][4] = {};
  gemm128_core(Ag, Bg, smem, acc);
  const int tid = threadIdx.x, lane = tid & 63, wave = tid >> 6;
  const int wm = (wave & 1) * 64, wn = (wave >> 1) * 64;
  const int r = lane & 15, quad = lane >> 4;
#pragma unroll
  for (int i = 0; i < 4; ++i)
#pragma unroll
    for (int reg = 0; reg < 4; ++reg) {
      int m = blockIdx.x * 128 + wm + i * 16 + quad * 4 + reg;
      float sm = rsqrtf(Ssum[m] * (1.f / 1024.f) + 1e-6f);
#pragma unroll
      for (int j = 0; j < 4; ++j) {
        int n = blockIdx.y * 128 + wn + j * 16 + r;
        out[(size_t)m * 1024 + n] = acc[i][j][reg] * sm;
      }
    }
}

// ---------------------------------------------------------------------------
extern "C" void kernel_launch(void* const* d_in, const int* in_sizes, int n_in,
                              void* d_out, int out_size, void* d_ws, size_t ws_size,
                              hipStream_t stream) {
  const float* x  = (const float*)d_in[0];
  const float* Wq = (const float*)d_in[1];
  const float* Wk = (const float*)d_in[2];
  const float* Wv = (const float*)d_in[3];
  const float* Wo = (const float*)d_in[4];
  const float* nw = (const float*)d_in[5];
  float* out = (float*)d_out;
  char* ws = (char*)d_ws;

  u16* Xb   = (u16*)(ws + 0);            // 16 MB
  u16* Wqb  = (u16*)(ws + 16777216);
  u16* Wkb  = (u16*)(ws + 18874368);
  u16* Wvb  = (u16*)(ws + 20971520);
  u16* Wob  = (u16*)(ws + 23068672);
  u16* Qb   = (u16*)(ws + 25165824);     // 16 MB
  u16* Kb   = (u16*)(ws + 41943040);     // 16 MB
  u16* Vb   = (u16*)(ws + 58720256);     // 16 MB
  u16* Obf  = (u16*)(ws + 75497472);     // 16 MB scan output
  float* Sv = (float*)(ws + 92274688);   // 32 KB row sum-of-squares

  cast_all<<<12320, 256, 0, stream>>>(x, Wq, Wk, Wv, Wo, nw, Xb, Wqb, Wkb, Wvb, Wob, Sv);

  hgru_gemm_qkv8<<<384, 512, 0, stream>>>(Xb, Wqb, Wkb, Wvb, Qb, Kb, Vb);
  hgru_scan<<<4096, 256, 0, stream>>>(Qb, Kb, Vb, Obf, Sv);
  dim3 go(64, 8);
  hgru_gemm_out<<<go, 256, 0, stream>>>(Obf, Wob, Sv, out);
}

// Round 4
// 224.357 us; speedup vs baseline: 1.0268x; 1.0268x over previous
//
#include <hip/hip_runtime.h>
#include <cstdint>
#include <cstddef>

// ---------------------------------------------------------------------------
// Hgru2 (GLA-style gated linear attention), B=4, N=2048, d=1024, h=8, hd=128
//   cast_all: x,W -> bf16 (Wo gets norm_w folded); zeroes Ssum
//   gemm_qkv: Q=silu(xWq^T), K=1-sigmoid(xWk^T) (bf16), V (bf16)
//   hgru_scan (C=32): recompute U_{c-1} from chunk c-1 (1-term state, decay
//       <= e^-10); O = tril(Qh Kt^T) V + Qh U; fused sumsq via atomicAdd.
//   gemm_out: out[m][n] = rsqrt(Ssum[m]/1024+eps) * (O @ (Wo . w)^T)[m][n]
// R15: revert qkv to the R11 128x128 core (256x256/8-phase falsified: three
//      schedule variants all 23-26% MfmaUtil vs 29% for this core). Fix the
//      core's 4-way LDS bank conflict (6.29M cycles = 4/read): swizzle chunk
//      on (r>>1)&3 instead of r&3 -> 8 consecutive lanes cover all 8 bank
//      groups (collision only r vs r+8 = 2-way = free). Write side: global
//      pre-swizzle constant (tid>>3)&3. Bit-identical staging data.
// ---------------------------------------------------------------------------

typedef unsigned short u16;
using f32x4  = __attribute__((ext_vector_type(4))) float;
using bf16x8 = __attribute__((ext_vector_type(8))) short;

__device__ __forceinline__ float bf2f(u16 u) {
  union { unsigned int i; float f; } v; v.i = ((unsigned int)u) << 16; return v.f;
}
__device__ __forceinline__ u16 f2bf(float f) {
  union { float f; unsigned int i; } v; v.f = f;
  unsigned int r = v.i + 0x7fffu + ((v.i >> 16) & 1u);
  return (u16)(r >> 16);
}
__device__ __forceinline__ void async_load16(const void* g, void* l) {
  __builtin_amdgcn_global_load_lds(
      (const __attribute__((address_space(1))) unsigned int*)(uintptr_t)g,
      (__attribute__((address_space(3))) unsigned int*)(uintptr_t)l, 16, 0, 0);
}
// logsigmoid(f) for f in (0,1): softplus series, |err| <= 2.5e-5
__device__ __forceinline__ float logsig01(float f) {
  float u = f * f;
  return -0.69314718f + 0.5f * f + u * (-0.125f + u * (0.0052083335f - u * 3.472222e-4f));
}

// ---------------------------------------------------------------------------
// 128x128-tile bf16 GEMM core: BK=32, double-buffered in 32KB, 1 barrier/kt,
// loads age a full compute phase before the drain.
// R15 swizzle: LDS[row][c] = global[row][c ^ ((row>>1)&3)]; read chunk
// (quad ^ ((r>>1)&3)) -> 8 consecutive lanes hit 8 distinct 4-bank groups
// (was r&3: lanes r,r+4,r+8,r+12 same group = 4-way conflict, 6.29M cycles).
// ---------------------------------------------------------------------------
__device__ __forceinline__ void gemm128_core(const u16* __restrict__ Ag, const u16* __restrict__ Bg,
                                             u16* smem, f32x4 (&acc)[4][4]) {
  const int tid = threadIdx.x;
  const int lane = tid & 63, wave = tid >> 6;
  const int wm = (wave & 1) * 64, wn = (wave >> 1) * 64;
  const int r = lane & 15, quad = lane >> 4;
  const int xk = (r >> 1) & 3;                          // R15: was r & 3
  const u16* baseA = smem + (wm + r) * 32 + ((quad ^ xk) & 3) * 8;
  const u16* baseB = smem + 4096 + (wn + r) * 32 + ((quad ^ xk) & 3) * 8;
  const int soff = (tid >> 2) * 1024 + (((tid & 3) ^ ((tid >> 3) & 3)) * 8);  // R15: was (tid>>2)&3
  u16* dA = smem + wave * 512;           // + it*2048 + buf*8192
  u16* dB = smem + 4096 + wave * 512;
#pragma unroll
  for (int it = 0; it < 2; ++it) {
    async_load16(Ag + it * 65536 + soff, dA + it * 2048);
    async_load16(Bg + it * 65536 + soff, dB + it * 2048);
  }
#pragma unroll 2
  for (int kt = 0; kt < 32; ++kt) {
    const int cb = (kt & 1) * 8192;
    __syncthreads();
    if (kt < 31) {
      const int nb = ((kt + 1) & 1) * 8192;
      const u16* As = Ag + (kt + 1) * 32 + soff;
      const u16* Bs = Bg + (kt + 1) * 32 + soff;
#pragma unroll
      for (int it = 0; it < 2; ++it) {
        async_load16(As + it * 65536, dA + nb + it * 2048);
        async_load16(Bs + it * 65536, dB + nb + it * 2048);
      }
    }
    bf16x8 af[4], bv[4];
#pragma unroll
    for (int i = 0; i < 4; ++i) af[i] = *(const bf16x8*)(baseA + cb + i * 512);
#pragma unroll
    for (int j = 0; j < 4; ++j) bv[j] = *(const bf16x8*)(baseB + cb + j * 512);
#pragma unroll
    for (int i = 0; i < 4; ++i)
#pragma unroll
      for (int j = 0; j < 4; ++j)
        acc[i][j] = __builtin_amdgcn_mfma_f32_16x16x32_bf16(af[i], bv[j], acc[i][j], 0, 0, 0);
  }
}

// ---------------------------------------------------------------------------
// merged casts + Ssum zero: blocks 0-8191 -> x; 8192-12287 -> weights
// (Wo folds norm_w); 12288-12319 -> zero Ssum (8192 f32).
__global__ __launch_bounds__(256) void cast_all(
    const float* __restrict__ x, const float* __restrict__ w0, const float* __restrict__ w1,
    const float* __restrict__ w2, const float* __restrict__ w3, const float* __restrict__ nw,
    u16* __restrict__ xd, u16* __restrict__ d0, u16* __restrict__ d1,
    u16* __restrict__ d2, u16* __restrict__ d3, float* __restrict__ Sv) {
  const int blk = blockIdx.x;
  if (blk >= 12288) {
    Sv[(blk - 12288) * 256 + threadIdx.x] = 0.f;
    return;
  }
  const float* src;
  u16* dst;
  int i;
  bool fold = false;
  if (blk < 8192) {
    src = x; dst = xd; i = blk * 256 + threadIdx.x;
  } else {
    int wb = blk - 8192, which = wb >> 10;
    i = (wb & 1023) * 256 + threadIdx.x;
    src = which == 0 ? w0 : (which == 1 ? w1 : (which == 2 ? w2 : w3));
    dst = which == 0 ? d0 : (which == 1 ? d1 : (which == 2 ? d2 : d3));
    fold = (which == 3);
  }
  float4 v = ((const float4*)src)[i];
  if (fold) {
    float4 wv = ((const float4*)nw)[i & 255];
    v.x *= wv.x; v.y *= wv.y; v.z *= wv.z; v.w *= wv.w;
  }
  unsigned int lo = (unsigned)f2bf(v.x) | ((unsigned)f2bf(v.y) << 16);
  unsigned int hi = (unsigned)f2bf(v.z) | ((unsigned)f2bf(v.w) << 16);
  ((uint2*)dst)[i] = make_uint2(lo, hi);
}

// grid (64, 24): y/8 selects {Q,K,V}, y&7 = 128-col block
__global__ __launch_bounds__(256) void hgru_gemm_qkv(
    const u16* __restrict__ Xb, const u16* __restrict__ Wqb, const u16* __restrict__ Wkb,
    const u16* __restrict__ Wvb, u16* __restrict__ Qb, u16* __restrict__ Kb,
    u16* __restrict__ Vb) {
  __shared__ alignas(16) u16 smem[16384];
  const int which = blockIdx.y >> 3, bn = blockIdx.y & 7;
  const u16* W = which == 0 ? Wqb : (which == 1 ? Wkb : Wvb);
  const u16* Ag = Xb + (size_t)blockIdx.x * 128 * 1024;
  const u16* Bg = W + (size_t)bn * 128 * 1024;
  f32x4 acc[4][4] = {};
  gemm128_core(Ag, Bg, smem, acc);
  const int tid = threadIdx.x, lane = tid & 63, wave = tid >> 6;
  const int wm = (wave & 1) * 64, wn = (wave >> 1) * 64;
  const int r = lane & 15, quad = lane >> 4;
#pragma unroll
  for (int i = 0; i < 4; ++i)
#pragma unroll
    for (int j = 0; j < 4; ++j)
#pragma unroll
      for (int reg = 0; reg < 4; ++reg) {
        int m = blockIdx.x * 128 + wm + i * 16 + quad * 4 + reg;
        int n = bn * 128 + wn + j * 16 + r;
        size_t off = (size_t)m * 1024 + n;
        float z = acc[i][j][reg];
        if (which == 0) {
          Qb[off] = f2bf(z / (1.f + __expf(-z)));      // silu
        } else if (which == 1) {
          float ek = __expf(-z);
          Kb[off] = f2bf(ek / (1.f + ek));              // k = 1 - sigmoid(z)
        } else {
          Vb[off] = f2bf(z);
        }
      }
}

// ---------------------------------------------------------------------------
// Fused scan, 4-barrier structure, LDS 40448 B -> 4 blocks/CU.
// grid 4096: vh = blk&1, c = (blk>>1)&63 (C=32), bh = blk>>7.
// P0: column-owner cumsum+transforms (the ONLY global-latency phase)
//     half 0 (tid<128, col i): chunk c-1, 2-pass -> sKt[i][s] = k*exp(bC-b_s)
//     half 1 (col j): chunk c, 1-pass -> sQ[t][j]=q*exp(b), sK[t][j]=k*exp(-b)
//     all: V^T scatters from uint4-prefetched regs.
// P1: U-GEMM (regs) + GEMM1 -> sAm.   P2: spill U -> sU (overlays dead sKt).
// P3: GEMM2 + ssq atomics + stage O tile in sO.   P4: coalesced uint4 O-store.
// ---------------------------------------------------------------------------
__global__ __launch_bounds__(256, 4) void hgru_scan(
    const u16* __restrict__ Qg, const u16* __restrict__ Kg, const u16* __restrict__ Vg,
    u16* __restrict__ O, float* __restrict__ Ssum) {
  __shared__ alignas(16) char smem[40448];
  u16* sKt  = (u16*)(smem);                // [128][40] khat^T   [0,10240)
  u16* sVt1 = (u16*)(smem + 10240);        // [64][40]  V^T c-1  [10240,15360)
  u16* sK   = (u16*)(smem + 15360);        // [32][136] Kt       [15360,24064)
  u16* sQ   = (u16*)(smem + 24064);        // [32][136] Qh       [24064,32768)
  u16* sVt2 = (u16*)(smem + 32768);        // [64][40]  V^T c    [32768,37888)
  u16* sAm  = (u16*)(smem + 37888);        // [32][40]  masked A [37888,40448)
  u16* sU   = (u16*)(smem);                // [64][136] U^T      (after B1, over dead sKt+sVt1)
  u16* sO   = (u16*)(smem + 17408);        // [32][72]  O tile   (after B1, in dead sK head)

  const int tid = threadIdx.x, blk = blockIdx.x;
  const int vh = blk & 1, c = (blk >> 1) & 63, bh = blk >> 7, h = bh & 7, bb_ = bh >> 3;
  const size_t rb = (size_t)(bb_ * 2048 + c * 32) * 1024 + h * 128;
  const bool haveP = (c > 0);
  const size_t rb1 = haveP ? rb - 32 * 1024 : rb;

  const int lane = tid & 63, wave = tid >> 6;
  const int r = lane & 15, quad = lane >> 4;
  const int ts = tid & 31, g8 = tid >> 5;

  // V prefetch (uint4) + V^T scatters
  uint4 V2 = *(const uint4*)(Vg + rb  + (size_t)ts * 1024 + vh * 64 + g8 * 8);
  uint4 V1 = *(const uint4*)(Vg + rb1 + (size_t)ts * 1024 + vh * 64 + g8 * 8);
  { const u16* vp = (const u16*)&V2;
#pragma unroll
    for (int e = 0; e < 8; ++e) sVt2[(g8 * 8 + e) * 40 + ts] = vp[e]; }
  if (haveP) {
    const u16* vp = (const u16*)&V1;
#pragma unroll
    for (int e = 0; e < 8; ++e) sVt1[(g8 * 8 + e) * 40 + ts] = vp[e];
  }

  // P0: column cumsum + transforms
  const int col = tid & 127;
  if (tid < 128) {
    if (haveP) {
      const u16* kc = Kg + rb1 + col;
      unsigned int kraw[16];
      float bC = 0.f;
#pragma unroll
      for (int t = 0; t < 16; ++t) {
        unsigned int a = kc[(size_t)(2 * t) * 1024];
        unsigned int b = kc[(size_t)(2 * t + 1) * 1024];
        kraw[t] = a | (b << 16);
        bC += logsig01(1.f - bf2f((u16)a)) + logsig01(1.f - bf2f((u16)b));
      }
      float run = 0.f;
#pragma unroll
      for (int t = 0; t < 16; ++t) {
        float ka = bf2f((u16)(kraw[t] & 0xffff));
        float kb = bf2f((u16)(kraw[t] >> 16));
        run += logsig01(1.f - ka);
        sKt[col * 40 + 2 * t]     = f2bf(ka * __expf(bC - run));
        run += logsig01(1.f - kb);
        sKt[col * 40 + 2 * t + 1] = f2bf(kb * __expf(bC - run));
      }
    }
  } else {
    const u16* kc = Kg + rb + col;
    const u16* qc = Qg + rb + col;
    float run = 0.f;
#pragma unroll
    for (int t = 0; t < 32; ++t) {
      u16 ku = kc[(size_t)t * 1024];
      u16 qu = qc[(size_t)t * 1024];
      float kv = bf2f(ku);
      run += logsig01(1.f - kv);
      sQ[t * 136 + col] = f2bf(bf2f(qu) * __expf(run));
      sK[t * 136 + col] = f2bf(kv * __expf(-run));
    }
  }
  __syncthreads();  // B0

  // P1: U-GEMM (into regs) + GEMM1 -> sAm
  f32x4 accU[2][4] = {};
  const int vm = (wave & 1) * 32, in = (wave >> 1) * 64;
  if (haveP) {
#pragma unroll
    for (int mi = 0; mi < 2; ++mi) {
      bf16x8 af = *(const bf16x8*)(sVt1 + (vm + mi * 16 + r) * 40 + quad * 8);
#pragma unroll
      for (int nj = 0; nj < 4; ++nj) {
        bf16x8 bv = *(const bf16x8*)(sKt + (in + nj * 16 + r) * 40 + quad * 8);
        accU[mi][nj] = __builtin_amdgcn_mfma_f32_16x16x32_bf16(af, bv, accU[mi][nj], 0, 0, 0);
      }
    }
  }
  { const int mi = wave & 1, nj = wave >> 1;
    f32x4 a1 = {0.f, 0.f, 0.f, 0.f};
#pragma unroll
    for (int ks = 0; ks < 4; ++ks) {
      bf16x8 af = *(const bf16x8*)(sQ + (mi * 16 + r) * 136 + ks * 32 + quad * 8);
      bf16x8 bk = *(const bf16x8*)(sK + (nj * 16 + r) * 136 + ks * 32 + quad * 8);
      a1 = __builtin_amdgcn_mfma_f32_16x16x32_bf16(af, bk, a1, 0, 0, 0);
    }
#pragma unroll
    for (int reg = 0; reg < 4; ++reg) {
      int t = mi * 16 + quad * 4 + reg, s = nj * 16 + r;
      sAm[t * 40 + s] = (s <= t) ? f2bf(a1[reg]) : (u16)0;
    } }
  __syncthreads();  // B1

  // P2: spill U accumulator -> sU (overlays dead sKt/sVt1)
  if (haveP) {
#pragma unroll
    for (int mi = 0; mi < 2; ++mi)
#pragma unroll
      for (int nj = 0; nj < 4; ++nj)
#pragma unroll
        for (int reg = 0; reg < 4; ++reg) {
          int vl = vm + mi * 16 + quad * 4 + reg;
          int i  = in + nj * 16 + r;
          sU[vl * 136 + i] = f2bf(accU[mi][nj][reg]);
        }
  }
  __syncthreads();  // B2

  // P3: GEMM2 + fused sumsq + stage O tile
  { const int mi = wave & 1, no = (wave >> 1) * 32;
    bf16x8 af0 = *(const bf16x8*)(sAm + (mi * 16 + r) * 40 + quad * 8);
    bf16x8 afq[4];
    if (haveP) {
#pragma unroll
      for (int ks = 0; ks < 4; ++ks)
        afq[ks] = *(const bf16x8*)(sQ + (mi * 16 + r) * 136 + ks * 32 + quad * 8);
    }
    f32x4 ssq = {0.f, 0.f, 0.f, 0.f};
#pragma unroll
    for (int j = 0; j < 2; ++j) {
      f32x4 acc2 = {0.f, 0.f, 0.f, 0.f};
      bf16x8 bv0 = *(const bf16x8*)(sVt2 + (no + j * 16 + r) * 40 + quad * 8);
      acc2 = __builtin_amdgcn_mfma_f32_16x16x32_bf16(af0, bv0, acc2, 0, 0, 0);
      if (haveP) {
#pragma unroll
        for (int ks = 0; ks < 4; ++ks) {
          bf16x8 bs = *(const bf16x8*)(sU + (no + j * 16 + r) * 136 + ks * 32 + quad * 8);
          acc2 = __builtin_amdgcn_mfma_f32_16x16x32_bf16(afq[ks], bs, acc2, 0, 0, 0);
        }
      }
      ssq += acc2 * acc2;
#pragma unroll
      for (int reg = 0; reg < 4; ++reg) {
        int t = mi * 16 + quad * 4 + reg;
        sO[t * 72 + no + j * 16 + r] = f2bf(acc2[reg]);
      }
    }
    const int rowg = bb_ * 2048 + c * 32 + mi * 16 + quad * 4;
#pragma unroll
    for (int reg = 0; reg < 4; ++reg) {
      float v = ssq[reg];
      v += __shfl_xor(v, 1); v += __shfl_xor(v, 2);
      v += __shfl_xor(v, 4); v += __shfl_xor(v, 8);
      if (r == 0) atomicAdd(&Ssum[rowg + reg], v);
    } }
  __syncthreads();  // B3

  // P4: coalesced O store (uint4: 128B per 8 threads)
  { const int row = tid >> 3, seg = tid & 7;
    *(uint4*)(O + rb + (size_t)row * 1024 + vh * 64 + seg * 8) =
        *(const uint4*)(sO + row * 72 + seg * 8); }
}

// out[m][n] = rsqrt(Ssum[m]/1024+eps) * (O @ Wo'^T)[m][n]; grid (64,8)
__global__ __launch_bounds__(256) void hgru_gemm_out(const u16* __restrict__ Ab,
                                                     const u16* __restrict__ Wob,
                                                     const float* __restrict__ Ssum,
                                                     float* __restrict__ out) {
  __shared__ alignas(16) u16 smem[16384];
  const u16* Ag = Ab + (size_t)blockIdx.x * 128 * 1024;
  const u16* Bg = Wob + (size_t)blockIdx.y * 128 * 1024;
  f32x4 acc[4][4] = {};
  gemm128_core(Ag, Bg, smem, acc);
  const int tid = threadIdx.x, lane = tid & 63, wave = tid >> 6;
  const int wm = (wave & 1) * 64, wn = (wave >> 1) * 64;
  const int r = lane & 15, quad = lane >> 4;
#pragma unroll
  for (int i = 0; i < 4; ++i)
#pragma unroll
    for (int reg = 0; reg < 4; ++reg) {
      int m = blockIdx.x * 128 + wm + i * 16 + quad * 4 + reg;
      float sm = rsqrtf(Ssum[m] * (1.f / 1024.f) + 1e-6f);
#pragma unroll
      for (int j = 0; j < 4; ++j) {
        int n = blockIdx.y * 128 + wn + j * 16 + r;
        out[(size_t)m * 1024 + n] = acc[i][j][reg] * sm;
      }
    }
}

// ---------------------------------------------------------------------------
extern "C" void kernel_launch(void* const* d_in, const int* in_sizes, int n_in,
                              void* d_out, int out_size, void* d_ws, size_t ws_size,
                              hipStream_t stream) {
  const float* x  = (const float*)d_in[0];
  const float* Wq = (const float*)d_in[1];
  const float* Wk = (const float*)d_in[2];
  const float* Wv = (const float*)d_in[3];
  const float* Wo = (const float*)d_in[4];
  const float* nw = (const float*)d_in[5];
  float* out = (float*)d_out;
  char* ws = (char*)d_ws;

  u16* Xb   = (u16*)(ws + 0);            // 16 MB
  u16* Wqb  = (u16*)(ws + 16777216);
  u16* Wkb  = (u16*)(ws + 18874368);
  u16* Wvb  = (u16*)(ws + 20971520);
  u16* Wob  = (u16*)(ws + 23068672);
  u16* Qb   = (u16*)(ws + 25165824);     // 16 MB
  u16* Kb   = (u16*)(ws + 41943040);     // 16 MB
  u16* Vb   = (u16*)(ws + 58720256);     // 16 MB
  u16* Obf  = (u16*)(ws + 75497472);     // 16 MB scan output
  float* Sv = (float*)(ws + 92274688);   // 32 KB row sum-of-squares

  cast_all<<<12320, 256, 0, stream>>>(x, Wq, Wk, Wv, Wo, nw, Xb, Wqb, Wkb, Wvb, Wob, Sv);

  dim3 gq(64, 24);
  hgru_gemm_qkv<<<gq, 256, 0, stream>>>(Xb, Wqb, Wkb, Wvb, Qb, Kb, Vb);
  hgru_scan<<<4096, 256, 0, stream>>>(Qb, Kb, Vb, Obf, Sv);
  dim3 go(64, 8);
  hgru_gemm_out<<<go, 256, 0, stream>>>(Obf, Wob, Sv, out);
}

// Round 6
// 224.258 us; speedup vs baseline: 1.0273x; 1.0004x over previous
//
#include <hip/hip_runtime.h>
#include <cstdint>
#include <cstddef>

// ---------------------------------------------------------------------------
// Hgru2 (GLA-style gated linear attention), B=4, N=2048, d=1024, h=8, hd=128
//   cast_all: x,W -> bf16 (Wo gets norm_w folded); zeroes Ssum
//   gemm_qkv: Q=silu(xWq^T), K=1-sigmoid(xWk^T) (bf16), V (bf16)
//   hgru_scan (C=32): recompute U_{c-1} from chunk c-1 (1-term state, decay
//       <= e^-10); O = tril(Qh Kt^T) V + Qh U; fused sumsq via atomicAdd.
//   gemm_out: out[m][n] = rsqrt(Ssum[m]/1024+eps) * (O @ (Wo . w)^T)[m][n]
// R17: R16 epilogue fix — store loop now covers the FULL 128-wide tile:
//      row16=tid>>4, seg=tid&15, 8 uint4 stores/thread (R16 used seg=tid&7,
//      4 stores -> only cols 0-63 written, absmax 2.73). Coalesced: 16 lanes
//      = 256B contiguous. LDS stride 136 u16 -> 2-way alias only (free).
//      (R15 kept: conflict-free swizzle xk=(r>>1)&3, 0 LDS conflicts.)
// ---------------------------------------------------------------------------

typedef unsigned short u16;
using f32x4  = __attribute__((ext_vector_type(4))) float;
using bf16x8 = __attribute__((ext_vector_type(8))) short;

__device__ __forceinline__ float bf2f(u16 u) {
  union { unsigned int i; float f; } v; v.i = ((unsigned int)u) << 16; return v.f;
}
__device__ __forceinline__ u16 f2bf(float f) {
  union { float f; unsigned int i; } v; v.f = f;
  unsigned int r = v.i + 0x7fffu + ((v.i >> 16) & 1u);
  return (u16)(r >> 16);
}
__device__ __forceinline__ void async_load16(const void* g, void* l) {
  __builtin_amdgcn_global_load_lds(
      (const __attribute__((address_space(1))) unsigned int*)(uintptr_t)g,
      (__attribute__((address_space(3))) unsigned int*)(uintptr_t)l, 16, 0, 0);
}
// logsigmoid(f) for f in (0,1): softplus series, |err| <= 2.5e-5
__device__ __forceinline__ float logsig01(float f) {
  float u = f * f;
  return -0.69314718f + 0.5f * f + u * (-0.125f + u * (0.0052083335f - u * 3.472222e-4f));
}

// ---------------------------------------------------------------------------
// 128x128-tile bf16 GEMM core: BK=32, double-buffered in 32KB, 1 barrier/kt,
// loads age a full compute phase before the drain.
// R15 swizzle: LDS[row][c] = global[row][c ^ ((row>>1)&3)]; read chunk
// (quad ^ ((r>>1)&3)) -> conflict-free b128 reads (verified 0 conflicts).
// ---------------------------------------------------------------------------
__device__ __forceinline__ void gemm128_core(const u16* __restrict__ Ag, const u16* __restrict__ Bg,
                                             u16* smem, f32x4 (&acc)[4][4]) {
  const int tid = threadIdx.x;
  const int lane = tid & 63, wave = tid >> 6;
  const int wm = (wave & 1) * 64, wn = (wave >> 1) * 64;
  const int r = lane & 15, quad = lane >> 4;
  const int xk = (r >> 1) & 3;
  const u16* baseA = smem + (wm + r) * 32 + ((quad ^ xk) & 3) * 8;
  const u16* baseB = smem + 4096 + (wn + r) * 32 + ((quad ^ xk) & 3) * 8;
  const int soff = (tid >> 2) * 1024 + (((tid & 3) ^ ((tid >> 3) & 3)) * 8);
  u16* dA = smem + wave * 512;           // + it*2048 + buf*8192
  u16* dB = smem + 4096 + wave * 512;
#pragma unroll
  for (int it = 0; it < 2; ++it) {
    async_load16(Ag + it * 65536 + soff, dA + it * 2048);
    async_load16(Bg + it * 65536 + soff, dB + it * 2048);
  }
#pragma unroll 2
  for (int kt = 0; kt < 32; ++kt) {
    const int cb = (kt & 1) * 8192;
    __syncthreads();
    if (kt < 31) {
      const int nb = ((kt + 1) & 1) * 8192;
      const u16* As = Ag + (kt + 1) * 32 + soff;
      const u16* Bs = Bg + (kt + 1) * 32 + soff;
#pragma unroll
      for (int it = 0; it < 2; ++it) {
        async_load16(As + it * 65536, dA + nb + it * 2048);
        async_load16(Bs + it * 65536, dB + nb + it * 2048);
      }
    }
    bf16x8 af[4], bv[4];
#pragma unroll
    for (int i = 0; i < 4; ++i) af[i] = *(const bf16x8*)(baseA + cb + i * 512);
#pragma unroll
    for (int j = 0; j < 4; ++j) bv[j] = *(const bf16x8*)(baseB + cb + j * 512);
#pragma unroll
    for (int i = 0; i < 4; ++i)
#pragma unroll
      for (int j = 0; j < 4; ++j)
        acc[i][j] = __builtin_amdgcn_mfma_f32_16x16x32_bf16(af[i], bv[j], acc[i][j], 0, 0, 0);
  }
}

// ---------------------------------------------------------------------------
// merged casts + Ssum zero: blocks 0-8191 -> x; 8192-12287 -> weights
// (Wo folds norm_w); 12288-12319 -> zero Ssum (8192 f32).
__global__ __launch_bounds__(256) void cast_all(
    const float* __restrict__ x, const float* __restrict__ w0, const float* __restrict__ w1,
    const float* __restrict__ w2, const float* __restrict__ w3, const float* __restrict__ nw,
    u16* __restrict__ xd, u16* __restrict__ d0, u16* __restrict__ d1,
    u16* __restrict__ d2, u16* __restrict__ d3, float* __restrict__ Sv) {
  const int blk = blockIdx.x;
  if (blk >= 12288) {
    Sv[(blk - 12288) * 256 + threadIdx.x] = 0.f;
    return;
  }
  const float* src;
  u16* dst;
  int i;
  bool fold = false;
  if (blk < 8192) {
    src = x; dst = xd; i = blk * 256 + threadIdx.x;
  } else {
    int wb = blk - 8192, which = wb >> 10;
    i = (wb & 1023) * 256 + threadIdx.x;
    src = which == 0 ? w0 : (which == 1 ? w1 : (which == 2 ? w2 : w3));
    dst = which == 0 ? d0 : (which == 1 ? d1 : (which == 2 ? d2 : d3));
    fold = (which == 3);
  }
  float4 v = ((const float4*)src)[i];
  if (fold) {
    float4 wv = ((const float4*)nw)[i & 255];
    v.x *= wv.x; v.y *= wv.y; v.z *= wv.z; v.w *= wv.w;
  }
  unsigned int lo = (unsigned)f2bf(v.x) | ((unsigned)f2bf(v.y) << 16);
  unsigned int hi = (unsigned)f2bf(v.z) | ((unsigned)f2bf(v.w) << 16);
  ((uint2*)dst)[i] = make_uint2(lo, hi);
}

// grid (64, 24): y/8 selects {Q,K,V}, y&7 = 128-col block
// R17 epilogue: activate -> smem[128][136] -> coalesced uint4 stores
// (full 128-col coverage: 16 segs x 8 rows-per-thread).
__global__ __launch_bounds__(256) void hgru_gemm_qkv(
    const u16* __restrict__ Xb, const u16* __restrict__ Wqb, const u16* __restrict__ Wkb,
    const u16* __restrict__ Wvb, u16* __restrict__ Qb, u16* __restrict__ Kb,
    u16* __restrict__ Vb) {
  __shared__ alignas(16) u16 smem[17408];   // 34816 B (GEMM uses first 32768)
  const int which = blockIdx.y >> 3, bn = blockIdx.y & 7;
  const u16* W = which == 0 ? Wqb : (which == 1 ? Wkb : Wvb);
  const u16* Ag = Xb + (size_t)blockIdx.x * 128 * 1024;
  const u16* Bg = W + (size_t)bn * 128 * 1024;
  f32x4 acc[4][4] = {};
  gemm128_core(Ag, Bg, smem, acc);
  const int tid = threadIdx.x, lane = tid & 63, wave = tid >> 6;
  const int wm = (wave & 1) * 64, wn = (wave >> 1) * 64;
  const int r = lane & 15, quad = lane >> 4;

  __syncthreads();  // all waves done reading GEMM buffers
#pragma unroll
  for (int i = 0; i < 4; ++i)
#pragma unroll
    for (int j = 0; j < 4; ++j)
#pragma unroll
      for (int reg = 0; reg < 4; ++reg) {
        int ml = wm + i * 16 + quad * 4 + reg;
        int nl = wn + j * 16 + r;
        float z = acc[i][j][reg];
        float v;
        if (which == 0)      v = z / (1.f + __expf(-z));             // silu
        else if (which == 1) { float ek = __expf(-z); v = ek / (1.f + ek); }  // 1-sigmoid
        else                 v = z;
        smem[ml * 136 + nl] = f2bf(v);
      }
  __syncthreads();

  u16* __restrict__ dst = which == 0 ? Qb : (which == 1 ? Kb : Vb);
  const int row16 = tid >> 4, seg = tid & 15;
#pragma unroll
  for (int p = 0; p < 8; ++p) {
    int row = row16 + p * 16;
    *(uint4*)(dst + (size_t)(blockIdx.x * 128 + row) * 1024 + bn * 128 + seg * 8) =
        *(const uint4*)(smem + row * 136 + seg * 8);
  }
}

// ---------------------------------------------------------------------------
// Fused scan, 4-barrier structure, LDS 40448 B -> 4 blocks/CU.
// grid 4096: vh = blk&1, c = (blk>>1)&63 (C=32), bh = blk>>7.
// P0: column-owner cumsum+transforms (the ONLY global-latency phase)
//     half 0 (tid<128, col i): chunk c-1, 2-pass -> sKt[i][s] = k*exp(bC-b_s)
//     half 1 (col j): chunk c, 1-pass -> sQ[t][j]=q*exp(b), sK[t][j]=k*exp(-b)
//     all: V^T scatters from uint4-prefetched regs.
// P1: U-GEMM (regs) + GEMM1 -> sAm.   P2: spill U -> sU (overlays dead sKt).
// P3: GEMM2 + ssq atomics + stage O tile in sO.   P4: coalesced uint4 O-store.
// ---------------------------------------------------------------------------
__global__ __launch_bounds__(256, 4) void hgru_scan(
    const u16* __restrict__ Qg, const u16* __restrict__ Kg, const u16* __restrict__ Vg,
    u16* __restrict__ O, float* __restrict__ Ssum) {
  __shared__ alignas(16) char smem[40448];
  u16* sKt  = (u16*)(smem);                // [128][40] khat^T   [0,10240)
  u16* sVt1 = (u16*)(smem + 10240);        // [64][40]  V^T c-1  [10240,15360)
  u16* sK   = (u16*)(smem + 15360);        // [32][136] Kt       [15360,24064)
  u16* sQ   = (u16*)(smem + 24064);        // [32][136] Qh       [24064,32768)
  u16* sVt2 = (u16*)(smem + 32768);        // [64][40]  V^T c    [32768,37888)
  u16* sAm  = (u16*)(smem + 37888);        // [32][40]  masked A [37888,40448)
  u16* sU   = (u16*)(smem);                // [64][136] U^T      (after B1, over dead sKt+sVt1)
  u16* sO   = (u16*)(smem + 17408);        // [32][72]  O tile   (after B1, in dead sK head)

  const int tid = threadIdx.x, blk = blockIdx.x;
  const int vh = blk & 1, c = (blk >> 1) & 63, bh = blk >> 7, h = bh & 7, bb_ = bh >> 3;
  const size_t rb = (size_t)(bb_ * 2048 + c * 32) * 1024 + h * 128;
  const bool haveP = (c > 0);
  const size_t rb1 = haveP ? rb - 32 * 1024 : rb;

  const int lane = tid & 63, wave = tid >> 6;
  const int r = lane & 15, quad = lane >> 4;
  const int ts = tid & 31, g8 = tid >> 5;

  // V prefetch (uint4) + V^T scatters
  uint4 V2 = *(const uint4*)(Vg + rb  + (size_t)ts * 1024 + vh * 64 + g8 * 8);
  uint4 V1 = *(const uint4*)(Vg + rb1 + (size_t)ts * 1024 + vh * 64 + g8 * 8);
  { const u16* vp = (const u16*)&V2;
#pragma unroll
    for (int e = 0; e < 8; ++e) sVt2[(g8 * 8 + e) * 40 + ts] = vp[e]; }
  if (haveP) {
    const u16* vp = (const u16*)&V1;
#pragma unroll
    for (int e = 0; e < 8; ++e) sVt1[(g8 * 8 + e) * 40 + ts] = vp[e];
  }

  // P0: column cumsum + transforms
  const int col = tid & 127;
  if (tid < 128) {
    if (haveP) {
      const u16* kc = Kg + rb1 + col;
      unsigned int kraw[16];
      float bC = 0.f;
#pragma unroll
      for (int t = 0; t < 16; ++t) {
        unsigned int a = kc[(size_t)(2 * t) * 1024];
        unsigned int b = kc[(size_t)(2 * t + 1) * 1024];
        kraw[t] = a | (b << 16);
        bC += logsig01(1.f - bf2f((u16)a)) + logsig01(1.f - bf2f((u16)b));
      }
      float run = 0.f;
#pragma unroll
      for (int t = 0; t < 16; ++t) {
        float ka = bf2f((u16)(kraw[t] & 0xffff));
        float kb = bf2f((u16)(kraw[t] >> 16));
        run += logsig01(1.f - ka);
        sKt[col * 40 + 2 * t]     = f2bf(ka * __expf(bC - run));
        run += logsig01(1.f - kb);
        sKt[col * 40 + 2 * t + 1] = f2bf(kb * __expf(bC - run));
      }
    }
  } else {
    const u16* kc = Kg + rb + col;
    const u16* qc = Qg + rb + col;
    float run = 0.f;
#pragma unroll
    for (int t = 0; t < 32; ++t) {
      u16 ku = kc[(size_t)t * 1024];
      u16 qu = qc[(size_t)t * 1024];
      float kv = bf2f(ku);
      run += logsig01(1.f - kv);
      sQ[t * 136 + col] = f2bf(bf2f(qu) * __expf(run));
      sK[t * 136 + col] = f2bf(kv * __expf(-run));
    }
  }
  __syncthreads();  // B0

  // P1: U-GEMM (into regs) + GEMM1 -> sAm
  f32x4 accU[2][4] = {};
  const int vm = (wave & 1) * 32, in = (wave >> 1) * 64;
  if (haveP) {
#pragma unroll
    for (int mi = 0; mi < 2; ++mi) {
      bf16x8 af = *(const bf16x8*)(sVt1 + (vm + mi * 16 + r) * 40 + quad * 8);
#pragma unroll
      for (int nj = 0; nj < 4; ++nj) {
        bf16x8 bv = *(const bf16x8*)(sKt + (in + nj * 16 + r) * 40 + quad * 8);
        accU[mi][nj] = __builtin_amdgcn_mfma_f32_16x16x32_bf16(af, bv, accU[mi][nj], 0, 0, 0);
      }
    }
  }
  { const int mi = wave & 1, nj = wave >> 1;
    f32x4 a1 = {0.f, 0.f, 0.f, 0.f};
#pragma unroll
    for (int ks = 0; ks < 4; ++ks) {
      bf16x8 af = *(const bf16x8*)(sQ + (mi * 16 + r) * 136 + ks * 32 + quad * 8);
      bf16x8 bk = *(const bf16x8*)(sK + (nj * 16 + r) * 136 + ks * 32 + quad * 8);
      a1 = __builtin_amdgcn_mfma_f32_16x16x32_bf16(af, bk, a1, 0, 0, 0);
    }
#pragma unroll
    for (int reg = 0; reg < 4; ++reg) {
      int t = mi * 16 + quad * 4 + reg, s = nj * 16 + r;
      sAm[t * 40 + s] = (s <= t) ? f2bf(a1[reg]) : (u16)0;
    } }
  __syncthreads();  // B1

  // P2: spill U accumulator -> sU (overlays dead sKt/sVt1)
  if (haveP) {
#pragma unroll
    for (int mi = 0; mi < 2; ++mi)
#pragma unroll
      for (int nj = 0; nj < 4; ++nj)
#pragma unroll
        for (int reg = 0; reg < 4; ++reg) {
          int vl = vm + mi * 16 + quad * 4 + reg;
          int i  = in + nj * 16 + r;
          sU[vl * 136 + i] = f2bf(accU[mi][nj][reg]);
        }
  }
  __syncthreads();  // B2

  // P3: GEMM2 + fused sumsq + stage O tile
  { const int mi = wave & 1, no = (wave >> 1) * 32;
    bf16x8 af0 = *(const bf16x8*)(sAm + (mi * 16 + r) * 40 + quad * 8);
    bf16x8 afq[4];
    if (haveP) {
#pragma unroll
      for (int ks = 0; ks < 4; ++ks)
        afq[ks] = *(const bf16x8*)(sQ + (mi * 16 + r) * 136 + ks * 32 + quad * 8);
    }
    f32x4 ssq = {0.f, 0.f, 0.f, 0.f};
#pragma unroll
    for (int j = 0; j < 2; ++j) {
      f32x4 acc2 = {0.f, 0.f, 0.f, 0.f};
      bf16x8 bv0 = *(const bf16x8*)(sVt2 + (no + j * 16 + r) * 40 + quad * 8);
      acc2 = __builtin_amdgcn_mfma_f32_16x16x32_bf16(af0, bv0, acc2, 0, 0, 0);
      if (haveP) {
#pragma unroll
        for (int ks = 0; ks < 4; ++ks) {
          bf16x8 bs = *(const bf16x8*)(sU + (no + j * 16 + r) * 136 + ks * 32 + quad * 8);
          acc2 = __builtin_amdgcn_mfma_f32_16x16x32_bf16(afq[ks], bs, acc2, 0, 0, 0);
        }
      }
      ssq += acc2 * acc2;
#pragma unroll
      for (int reg = 0; reg < 4; ++reg) {
        int t = mi * 16 + quad * 4 + reg;
        sO[t * 72 + no + j * 16 + r] = f2bf(acc2[reg]);
      }
    }
    const int rowg = bb_ * 2048 + c * 32 + mi * 16 + quad * 4;
#pragma unroll
    for (int reg = 0; reg < 4; ++reg) {
      float v = ssq[reg];
      v += __shfl_xor(v, 1); v += __shfl_xor(v, 2);
      v += __shfl_xor(v, 4); v += __shfl_xor(v, 8);
      if (r == 0) atomicAdd(&Ssum[rowg + reg], v);
    } }
  __syncthreads();  // B3

  // P4: coalesced O store (uint4: 128B per 8 threads)
  { const int row = tid >> 3, seg = tid & 7;
    *(uint4*)(O + rb + (size_t)row * 1024 + vh * 64 + seg * 8) =
        *(const uint4*)(sO + row * 72 + seg * 8); }
}

// out[m][n] = rsqrt(Ssum[m]/1024+eps) * (O @ Wo'^T)[m][n]; grid (64,8)
__global__ __launch_bounds__(256) void hgru_gemm_out(const u16* __restrict__ Ab,
                                                     const u16* __restrict__ Wob,
                                                     const float* __restrict__ Ssum,
                                                     float* __restrict__ out) {
  __shared__ alignas(16) u16 smem[16384];
  const u16* Ag = Ab + (size_t)blockIdx.x * 128 * 1024;
  const u16* Bg = Wob + (size_t)blockIdx.y * 128 * 1024;
  f32x4 acc[4][4] = {};
  gemm128_core(Ag, Bg, smem, acc);
  const int tid = threadIdx.x, lane = tid & 63, wave = tid >> 6;
  const int wm = (wave & 1) * 64, wn = (wave >> 1) * 64;
  const int r = lane & 15, quad = lane >> 4;
#pragma unroll
  for (int i = 0; i < 4; ++i)
#pragma unroll
    for (int reg = 0; reg < 4; ++reg) {
      int m = blockIdx.x * 128 + wm + i * 16 + quad * 4 + reg;
      float sm = rsqrtf(Ssum[m] * (1.f / 1024.f) + 1e-6f);
#pragma unroll
      for (int j = 0; j < 4; ++j) {
        int n = blockIdx.y * 128 + wn + j * 16 + r;
        out[(size_t)m * 1024 + n] = acc[i][j][reg] * sm;
      }
    }
}

// ---------------------------------------------------------------------------
extern "C" void kernel_launch(void* const* d_in, const int* in_sizes, int n_in,
                              void* d_out, int out_size, void* d_ws, size_t ws_size,
                              hipStream_t stream) {
  const float* x  = (const float*)d_in[0];
  const float* Wq = (const float*)d_in[1];
  const float* Wk = (const float*)d_in[2];
  const float* Wv = (const float*)d_in[3];
  const float* Wo = (const float*)d_in[4];
  const float* nw = (const float*)d_in[5];
  float* out = (float*)d_out;
  char* ws = (char*)d_ws;

  u16* Xb   = (u16*)(ws + 0);            // 16 MB
  u16* Wqb  = (u16*)(ws + 16777216);
  u16* Wkb  = (u16*)(ws + 18874368);
  u16* Wvb  = (u16*)(ws + 20971520);
  u16* Wob  = (u16*)(ws + 23068672);
  u16* Qb   = (u16*)(ws + 25165824);     // 16 MB
  u16* Kb   = (u16*)(ws + 41943040);     // 16 MB
  u16* Vb   = (u16*)(ws + 58720256);     // 16 MB
  u16* Obf  = (u16*)(ws + 75497472);     // 16 MB scan output
  float* Sv = (float*)(ws + 92274688);   // 32 KB row sum-of-squares

  cast_all<<<12320, 256, 0, stream>>>(x, Wq, Wk, Wv, Wo, nw, Xb, Wqb, Wkb, Wvb, Wob, Sv);

  dim3 gq(64, 24);
  hgru_gemm_qkv<<<gq, 256, 0, stream>>>(Xb, Wqb, Wkb, Wvb, Qb, Kb, Vb);
  hgru_scan<<<4096, 256, 0, stream>>>(Qb, Kb, Vb, Obf, Sv);
  dim3 go(64, 8);
  hgru_gemm_out<<<go, 256, 0, stream>>>(Obf, Wob, Sv, out);
}